// Round 21
// baseline (192.860 us; speedup 1.0000x reference)
//
#include <hip/hip_runtime.h>
#include <hip/hip_fp16.h>

#define DDIM 128
#define ACC_BLOCKS 2048
#define NWALK (ACC_BLOCKS * 4)     // full-wave walkers
#define NGROUP 64                  // 2048 blocks / 32 per group

typedef unsigned int uint;
typedef unsigned short ushort;
typedef __attribute__((ext_vector_type(8))) short bf16x8;
typedef __attribute__((ext_vector_type(4))) float f32x4;

static __device__ __forceinline__ ushort f2bf(float x) {
    uint u = __float_as_uint(x);
    u += 0x7fffu + ((u >> 16) & 1u);   // RTN-even
    return (ushort)(u >> 16);
}

static __device__ __forceinline__ bf16x8 load_frag8(const float* base) {
    const float4 p = *reinterpret_cast<const float4*>(base);
    const float4 q = *reinterpret_cast<const float4*>(base + 4);
    bf16x8 f;
    f[0] = (short)f2bf(p.x); f[1] = (short)f2bf(p.y);
    f[2] = (short)f2bf(p.z); f[3] = (short)f2bf(p.w);
    f[4] = (short)f2bf(q.x); f[5] = (short)f2bf(q.y);
    f[6] = (short)f2bf(q.z); f[7] = (short)f2bf(q.w);
    return f;
}

// ---------------- Kernel A (fat): precompute_mfma (blocks < PB) + prep (rest) ----------
__global__ __launch_bounds__(256) void fat_prep_precompute(
    const float* __restrict__ impact,
    const float* __restrict__ W,
    const float* __restrict__ Mm,
    __half* __restrict__ WhH,
    __half* __restrict__ MhH,
    const int* __restrict__ segs,
    const int* __restrict__ node_ids,
    const int* __restrict__ neighbor_ids,
    int* __restrict__ items,
    int* __restrict__ wstart,
    int* __restrict__ counters,
    int T, int N, int E, int PB, int whoff, int mhoff)
{
    if ((int)blockIdx.x >= PB) {
        // ---------------- prep part ----------------
        const int x = ((int)blockIdx.x - PB) * 256 + (int)threadIdx.x;
        const int K = N + E;
        if (x <= NGROUP) counters[x] = 0;    // done2[0..63] + done3 at [64]

        if (x < E) {
            const int sc = segs[x];
            const int sp = (x == 0) ? -1 : segs[x - 1];
            const int sn = (x + 1 < E) ? segs[x + 1] : N;   // sentinel > any node

            items[x + sc + 1] = (mhoff + neighbor_ids[x] * 256)
                              | ((sn != sc) ? (int)0x80000000 : 0);

            for (int i = sp + 1; i <= sc; ++i)              // boundary nodes
                items[x + i] = (whoff + node_ids[i] * 256)
                             | ((i < sc) ? (int)0x80000000 : 0);

            if (x == E - 1) {
                for (int i = sc + 1; i < N; ++i)            // trailing deg-0 nodes
                    items[E + i] = (whoff + node_ids[i] * 256) | (int)0x80000000;
#pragma unroll
                for (int q = 0; q < 64; ++q) items[K + q] = whoff;  // pad
            }
        } else if (x >= E + 256 && x <= E + 256 + NWALK) {
            const int w = x - E - 256;
            int ws;
            if (w == 0) ws = 0;
            else {
                const long long t = (long long)w * E / NWALK;
                if (t >= E) ws = N + E;
                else {
                    const int n = segs[(int)t];
                    int lo = 0, hi = (int)t;
                    while (lo < hi) {
                        const int mid = (lo + hi) >> 1;
                        if (segs[mid] < n) lo = mid + 1; else hi = mid;
                    }
                    ws = lo + n;           // node n's Wh-item position
                }
            }
            wstart[w] = ws;
        }
        return;
    }

    // ---------------- precompute_mfma part ----------------
    const int lane = threadIdx.x & 63;
    const int wv   = threadIdx.x >> 6;       // 0..3 -> d tiles {2wv, 2wv+1}
    const int t0   = (int)blockIdx.x * 32;
    const int r16  = lane & 15;
    const int kg   = lane >> 4;              // 0..3

    bf16x8 A[2][4];
#pragma unroll
    for (int rt = 0; rt < 2; ++rt) {
        int t = t0 + rt * 16 + r16;
        if (t >= T) t = T - 1;               // clamp; writes masked below
        const float* abase = impact + (size_t)t * DDIM + kg * 8;
#pragma unroll
        for (int k0i = 0; k0i < 4; ++k0i)
            A[rt][k0i] = load_frag8(abase + k0i * 32);
    }

#pragma unroll
    for (int dti = 0; dti < 2; ++dti) {
        const int d0 = (wv * 2 + dti) * 16;
#pragma unroll
        for (int m = 0; m < 2; ++m) {
            const float* mat = (m == 0) ? W : Mm;
            __half* out = (m == 0) ? WhH : MhH;
            const float* bbase = mat + (size_t)(d0 + r16) * DDIM + kg * 8;
            f32x4 acc0 = {0.f, 0.f, 0.f, 0.f};
            f32x4 acc1 = {0.f, 0.f, 0.f, 0.f};
#pragma unroll
            for (int k0i = 0; k0i < 4; ++k0i) {
                const bf16x8 b = load_frag8(bbase + k0i * 32);
                acc0 = __builtin_amdgcn_mfma_f32_16x16x32_bf16(A[0][k0i], b, acc0, 0, 0, 0);
                acc1 = __builtin_amdgcn_mfma_f32_16x16x32_bf16(A[1][k0i], b, acc1, 0, 0, 0);
            }
            const int dcol = d0 + r16;
#pragma unroll
            for (int r = 0; r < 4; ++r) {
                const int tr0 = t0 + kg * 4 + r;
                const int tr1 = tr0 + 16;
                if (tr0 < T) out[(size_t)tr0 * DDIM + dcol] = __float2half(acc0[r]);
                if (tr1 < T) out[(size_t)tr1 * DDIM + dcol] = __float2half(acc1[r]);
            }
        }
    }
}

// ---------------- Kernel B: gather-accumulate + in-kernel tree reduce + softmax ------
// One wave per walker; R13-form saddr gather loop (verified local optimum).
// Epilogue: two-level done-counter reduction (all integer atomics; summation
// order fixed -> bit-deterministic). Group of 32 blocks -> last-finisher sums
// its 32 partials (overlaps other groups' gather tails); globally-last reducer
// does the 64-row final reduce + softmax. No third kernel.
__global__ __launch_bounds__(256, 8) void accumulate_items(
    const char* __restrict__ tab,
    const int* __restrict__ items,
    const int* __restrict__ wstart,
    float* __restrict__ partials,
    float* __restrict__ part2,
    int* __restrict__ counters,
    float* __restrict__ outv)
{
    const int lane = threadIdx.x & 63;
    const int wv   = __builtin_amdgcn_readfirstlane(threadIdx.x >> 6);
    const int w    = blockIdx.x * 4 + wv;

    const uint lb = (uint)lane << 2;     // 4 B per lane (2 fp16)

    const __half2 zero2 = __floats2half2_rn(0.f, 0.f);
    __half2 cc = zero2;
    float a0 = 0.f, a1 = 0.f;

    int k = __builtin_amdgcn_readfirstlane(wstart[w]);
    const int kend = __builtin_amdgcn_readfirstlane(wstart[w + 1]);

#define GATH(IW) (*reinterpret_cast<const __half2*>(tab + (((uint)(IW)) & 0x7fffffffu) + lb))
#define ACC(IW, V) { \
    cc = __hadd2(cc, V); \
    if ((IW) < 0) { \
        const float2 f = __half22float2(cc); \
        a0 += fmaxf(f.x, 0.f); a1 += fmaxf(f.y, 0.f); \
        cc = zero2; \
    } }
#define LOADI(Pa, Pb, Pc, Pd, kk) { \
    Pa = *reinterpret_cast<const int4*>(items + (kk)); \
    Pb = *reinterpret_cast<const int4*>(items + (kk) + 4); \
    Pc = *reinterpret_cast<const int4*>(items + (kk) + 8); \
    Pd = *reinterpret_cast<const int4*>(items + (kk) + 12); }
#define GATHER16(V, Pa, Pb, Pc, Pd) { \
    V[0] = GATH(Pa.x);  V[1] = GATH(Pa.y);  V[2]  = GATH(Pa.z);  V[3]  = GATH(Pa.w); \
    V[4] = GATH(Pb.x);  V[5] = GATH(Pb.y);  V[6]  = GATH(Pb.z);  V[7]  = GATH(Pb.w); \
    V[8] = GATH(Pc.x);  V[9] = GATH(Pc.y);  V[10] = GATH(Pc.z);  V[11] = GATH(Pc.w); \
    V[12] = GATH(Pd.x); V[13] = GATH(Pd.y); V[14] = GATH(Pd.z);  V[15] = GATH(Pd.w); }
#define ACC16(V, Pa, Pb, Pc, Pd) { \
    ACC(Pa.x, V[0]);  ACC(Pa.y, V[1]);  ACC(Pa.z, V[2]);   ACC(Pa.w, V[3]); \
    ACC(Pb.x, V[4]);  ACC(Pb.y, V[5]);  ACC(Pb.z, V[6]);   ACC(Pb.w, V[7]); \
    ACC(Pc.x, V[8]);  ACC(Pc.y, V[9]);  ACC(Pc.z, V[10]);  ACC(Pc.w, V[11]); \
    ACC(Pd.x, V[12]); ACC(Pd.y, V[13]); ACC(Pd.z, V[14]);  ACC(Pd.w, V[15]); }

    // head: align k to 16 (64 B scalar-load alignment)
    while (k < kend && (k & 15)) {
        const int iw = items[k];
        const __half2 v = GATH(iw);
        ACC(iw, v);
        ++k;
    }

    if (k + 32 <= kend) {
        int4 Aa, Ab, Ac, Ad, Ba, Bb, Bc, Bd;
        __half2 u[16], v[16];
        LOADI(Aa, Ab, Ac, Ad, k);
        GATHER16(u, Aa, Ab, Ac, Ad);
        LOADI(Ba, Bb, Bc, Bd, k + 16);
        k += 32;
        for (;;) {
            // phase 1: issue B's gathers, drain A
            GATHER16(v, Ba, Bb, Bc, Bd);
            ACC16(u, Aa, Ab, Ac, Ad);
            if (k + 16 <= kend) { LOADI(Aa, Ab, Ac, Ad, k); k += 16; }
            else { ACC16(v, Ba, Bb, Bc, Bd); break; }
            // phase 2: issue A's gathers, drain B
            GATHER16(u, Aa, Ab, Ac, Ad);
            ACC16(v, Ba, Bb, Bc, Bd);
            if (k + 16 <= kend) { LOADI(Ba, Bb, Bc, Bd, k); k += 16; }
            else { ACC16(u, Aa, Ab, Ac, Ad); break; }
        }
    }
    // tail
    while (k < kend) {
        const int iw = items[k];
        const __half2 v = GATH(iw);
        ACC(iw, v);
        ++k;
    }

    {   // range ends node-aligned -> cc==0; relu(0)=0 safe
        const float2 f = __half22float2(cc);
        a0 += fmaxf(f.x, 0.f);
        a1 += fmaxf(f.y, 0.f);
    }

    const int tid = threadIdx.x;
    __shared__ float red[4][DDIM];
    red[wv][lane * 2 + 0] = a0;
    red[wv][lane * 2 + 1] = a1;
    __syncthreads();
    if (tid < DDIM) {
        partials[(size_t)blockIdx.x * DDIM + tid] =
            red[0][tid] + red[1][tid] + red[2][tid] + red[3][tid];
    }

    // ---------------- level-1: last block of each 32-group reduces the group ------
    __threadfence();
    __shared__ int lastFlag;
    const int g = (int)blockIdx.x >> 5;
    if (tid == 0) lastFlag = (atomicAdd(&counters[g], 1) == 31) ? 1 : 0;
    __syncthreads();
    if (!lastFlag) return;
    __threadfence();                          // acquire group partials

    const int d = tid & (DDIM - 1);
    const int h = tid >> 7;                   // 0..1
    {
        float s = 0.f;
        const int r0 = g * 32;
        for (int r = r0 + h; r < r0 + 32; r += 2)
            s += partials[(size_t)r * DDIM + d];
        __shared__ float red2[2][DDIM];
        red2[h][d] = s;
        __syncthreads();
        if (tid < DDIM)
            part2[(size_t)g * DDIM + tid] = red2[0][tid] + red2[1][tid];
    }

    // ---------------- level-2: globally-last reducer does final reduce + softmax --
    __threadfence();
    __shared__ int last3;
    if (tid == 0) last3 = (atomicAdd(&counters[NGROUP], 1) == NGROUP - 1) ? 1 : 0;
    __syncthreads();
    if (!last3) return;
    __threadfence();                          // acquire part2

    float s = 0.f;
    for (int b = h; b < NGROUP; b += 2)
        s += part2[(size_t)b * DDIM + d];
    __shared__ float r2[2][DDIM];
    r2[h][d] = s;
    __syncthreads();

    __shared__ float vec[DDIM];
    __shared__ float tmp[DDIM];
    if (tid < DDIM) { const float v = r2[0][tid] + r2[1][tid]; vec[tid] = v; tmp[tid] = v; }
    __syncthreads();
    for (int o = 64; o > 0; o >>= 1) {
        if (tid < o) tmp[tid] = fmaxf(tmp[tid], tmp[tid + o]);
        __syncthreads();
    }
    const float mx = tmp[0];
    __syncthreads();
    float ev = 0.f;
    if (tid < DDIM) { ev = expf(vec[tid] - mx); tmp[tid] = ev; }
    __syncthreads();
    for (int o = 64; o > 0; o >>= 1) {
        if (tid < o) tmp[tid] += tmp[tid + o];
        __syncthreads();
    }
    if (tid < DDIM) outv[tid] = ev / tmp[0];
}

extern "C" void kernel_launch(void* const* d_in, const int* in_sizes, int n_in,
                              void* d_out, int out_size, void* d_ws, size_t ws_size,
                              hipStream_t stream) {
    const float* impact        = (const float*)d_in[0];
    const float* W             = (const float*)d_in[1];
    const float* Mm            = (const float*)d_in[2];
    const int*   node_ids      = (const int*)d_in[3];
    const int*   neighbor_ids  = (const int*)d_in[4];
    const int*   neighbor_segs = (const int*)d_in[5];

    const int T = in_sizes[0] / DDIM;   // 10000
    const int N = in_sizes[3];          // 50000
    const int E = in_sizes[4];          // 800000
    const int K = N + E;

    char* ws = (char*)d_ws;
    size_t off = 0;
    const int whoff = (int)off;
    __half* WhH = (__half*)(ws + off);  off += (size_t)T * DDIM * sizeof(__half);   // 2.56 MB
    const int mhoff = (int)off;
    __half* MhH = (__half*)(ws + off);  off += (size_t)T * DDIM * sizeof(__half);   // 2.56 MB
    float* partials = (float*)(ws + off); off += (size_t)ACC_BLOCKS * DDIM * sizeof(float);
    float* part2    = (float*)(ws + off); off += (size_t)NGROUP * DDIM * sizeof(float);
    int*   counters = (int*)(ws + off);   off += 256 * sizeof(int);  // done2[64] + done3
    off = (off + 255) & ~(size_t)255;                      // align for scalar item loads
    int*   items    = (int*)(ws + off);   off += (size_t)(K + 64) * sizeof(int);
    int*   wstart   = (int*)(ws + off);   off += (size_t)(NWALK + 1) * sizeof(int);
    float* outf     = (float*)d_out;

    const int PB    = (T + 31) / 32;                            // precompute blocks (313)
    const int PREPB = (E + 256 + NWALK + 1 + 255) / 256;        // prep blocks (incl. wstart)

    fat_prep_precompute<<<PB + PREPB, 256, 0, stream>>>(
        impact, W, Mm, WhH, MhH, neighbor_segs, node_ids, neighbor_ids,
        items, wstart, counters, T, N, E, PB, whoff, mhoff);
    accumulate_items<<<ACC_BLOCKS, 256, 0, stream>>>(ws, items, wstart, partials,
                                                     part2, counters, outf);
}

// Round 22
// 57.265 us; speedup vs baseline: 3.3679x; 3.3679x over previous
//
#include <hip/hip_runtime.h>
#include <hip/hip_fp16.h>

#define DDIM 128
#define ACC_BLOCKS 2048
#define NWALK (ACC_BLOCKS * 4)     // full-wave walkers
#define RED_BLOCKS 64

typedef unsigned int uint;
typedef unsigned short ushort;
typedef __attribute__((ext_vector_type(8))) short bf16x8;
typedef __attribute__((ext_vector_type(4))) float f32x4;

static __device__ __forceinline__ ushort f2bf(float x) {
    uint u = __float_as_uint(x);
    u += 0x7fffu + ((u >> 16) & 1u);   // RTN-even
    return (ushort)(u >> 16);
}

static __device__ __forceinline__ bf16x8 load_frag8(const float* base) {
    const float4 p = *reinterpret_cast<const float4*>(base);
    const float4 q = *reinterpret_cast<const float4*>(base + 4);
    bf16x8 f;
    f[0] = (short)f2bf(p.x); f[1] = (short)f2bf(p.y);
    f[2] = (short)f2bf(p.z); f[3] = (short)f2bf(p.w);
    f[4] = (short)f2bf(q.x); f[5] = (short)f2bf(q.y);
    f[6] = (short)f2bf(q.z); f[7] = (short)f2bf(q.w);
    return f;
}

// ---------------- Kernel A (fat): precompute_mfma (blocks < PB) + prep (rest) ----------
__global__ __launch_bounds__(256) void fat_prep_precompute(
    const float* __restrict__ impact,
    const float* __restrict__ W,
    const float* __restrict__ Mm,
    __half* __restrict__ WhH,
    __half* __restrict__ MhH,
    const int* __restrict__ segs,
    const int* __restrict__ node_ids,
    const int* __restrict__ neighbor_ids,
    int* __restrict__ items,
    int* __restrict__ wstart,
    int* __restrict__ done,
    int T, int N, int E, int PB, int whoff, int mhoff)
{
    if ((int)blockIdx.x >= PB) {
        // ---------------- prep part ----------------
        const int x = ((int)blockIdx.x - PB) * 256 + (int)threadIdx.x;
        const int K = N + E;
        if (x == 0) *done = 0;

        if (x < E) {
            const int sc = segs[x];
            const int sp = (x == 0) ? -1 : segs[x - 1];
            const int sn = (x + 1 < E) ? segs[x + 1] : N;   // sentinel > any node

            items[x + sc + 1] = (mhoff + neighbor_ids[x] * 256)
                              | ((sn != sc) ? (int)0x80000000 : 0);

            for (int i = sp + 1; i <= sc; ++i)              // boundary nodes
                items[x + i] = (whoff + node_ids[i] * 256)
                             | ((i < sc) ? (int)0x80000000 : 0);

            if (x == E - 1) {
                for (int i = sc + 1; i < N; ++i)            // trailing deg-0 nodes
                    items[E + i] = (whoff + node_ids[i] * 256) | (int)0x80000000;
#pragma unroll
                for (int q = 0; q < 64; ++q) items[K + q] = whoff;  // pad
            }
        } else if (x <= E + NWALK) {
            const int w = x - E;
            int ws;
            if (w == 0) ws = 0;
            else {
                const long long t = (long long)w * E / NWALK;
                if (t >= E) ws = N + E;
                else {
                    const int n = segs[(int)t];
                    int lo = 0, hi = (int)t;
                    while (lo < hi) {
                        const int mid = (lo + hi) >> 1;
                        if (segs[mid] < n) lo = mid + 1; else hi = mid;
                    }
                    ws = lo + n;           // node n's Wh-item position
                }
            }
            wstart[w] = ws;
        }
        return;
    }

    // ---------------- precompute_mfma part ----------------
    const int lane = threadIdx.x & 63;
    const int wv   = threadIdx.x >> 6;       // 0..3 -> d tiles {2wv, 2wv+1}
    const int t0   = (int)blockIdx.x * 32;
    const int r16  = lane & 15;
    const int kg   = lane >> 4;              // 0..3

    bf16x8 A[2][4];
#pragma unroll
    for (int rt = 0; rt < 2; ++rt) {
        int t = t0 + rt * 16 + r16;
        if (t >= T) t = T - 1;               // clamp; writes masked below
        const float* abase = impact + (size_t)t * DDIM + kg * 8;
#pragma unroll
        for (int k0i = 0; k0i < 4; ++k0i)
            A[rt][k0i] = load_frag8(abase + k0i * 32);
    }

#pragma unroll
    for (int dti = 0; dti < 2; ++dti) {
        const int d0 = (wv * 2 + dti) * 16;
#pragma unroll
        for (int m = 0; m < 2; ++m) {
            const float* mat = (m == 0) ? W : Mm;
            __half* out = (m == 0) ? WhH : MhH;
            const float* bbase = mat + (size_t)(d0 + r16) * DDIM + kg * 8;
            f32x4 acc0 = {0.f, 0.f, 0.f, 0.f};
            f32x4 acc1 = {0.f, 0.f, 0.f, 0.f};
#pragma unroll
            for (int k0i = 0; k0i < 4; ++k0i) {
                const bf16x8 b = load_frag8(bbase + k0i * 32);
                acc0 = __builtin_amdgcn_mfma_f32_16x16x32_bf16(A[0][k0i], b, acc0, 0, 0, 0);
                acc1 = __builtin_amdgcn_mfma_f32_16x16x32_bf16(A[1][k0i], b, acc1, 0, 0, 0);
            }
            const int dcol = d0 + r16;
#pragma unroll
            for (int r = 0; r < 4; ++r) {
                const int tr0 = t0 + kg * 4 + r;
                const int tr1 = tr0 + 16;
                if (tr0 < T) out[(size_t)tr0 * DDIM + dcol] = __float2half(acc0[r]);
                if (tr1 < T) out[(size_t)tr1 * DDIM + dcol] = __float2half(acc1[r]);
            }
        }
    }
}

// ---------------- Kernel B: pipelined item-stream gather-accumulate ----------------
// One wave per walker. Items scalar (s_load int4 -> SGPR); gathers saddr-form
// (scalar base + fixed lane*4 VGPR); lane = __half2 (2 features), ACC = 1
// v_pk_add_f16 per item; flush (wave-uniform branch) unpacks to fp32 at node
// boundaries. 2-deep batch pipeline: 32 gathers in flight per wave.
__global__ __launch_bounds__(256, 8) void accumulate_items(
    const char* __restrict__ tab,
    const int* __restrict__ items,
    const int* __restrict__ wstart,
    float* __restrict__ partials)
{
    const int lane = threadIdx.x & 63;
    const int wv   = __builtin_amdgcn_readfirstlane(threadIdx.x >> 6);
    const int w    = blockIdx.x * 4 + wv;

    const uint lb = (uint)lane << 2;     // 4 B per lane (2 fp16)

    const __half2 zero2 = __floats2half2_rn(0.f, 0.f);
    __half2 cc = zero2;
    float a0 = 0.f, a1 = 0.f;

    int k = __builtin_amdgcn_readfirstlane(wstart[w]);
    const int kend = __builtin_amdgcn_readfirstlane(wstart[w + 1]);

#define GATH(IW) (*reinterpret_cast<const __half2*>(tab + (((uint)(IW)) & 0x7fffffffu) + lb))
#define ACC(IW, V) { \
    cc = __hadd2(cc, V); \
    if ((IW) < 0) { \
        const float2 f = __half22float2(cc); \
        a0 += fmaxf(f.x, 0.f); a1 += fmaxf(f.y, 0.f); \
        cc = zero2; \
    } }
#define LOADI(Pa, Pb, Pc, Pd, kk) { \
    Pa = *reinterpret_cast<const int4*>(items + (kk)); \
    Pb = *reinterpret_cast<const int4*>(items + (kk) + 4); \
    Pc = *reinterpret_cast<const int4*>(items + (kk) + 8); \
    Pd = *reinterpret_cast<const int4*>(items + (kk) + 12); }
#define GATHER16(V, Pa, Pb, Pc, Pd) { \
    V[0] = GATH(Pa.x);  V[1] = GATH(Pa.y);  V[2]  = GATH(Pa.z);  V[3]  = GATH(Pa.w); \
    V[4] = GATH(Pb.x);  V[5] = GATH(Pb.y);  V[6]  = GATH(Pb.z);  V[7]  = GATH(Pb.w); \
    V[8] = GATH(Pc.x);  V[9] = GATH(Pc.y);  V[10] = GATH(Pc.z);  V[11] = GATH(Pc.w); \
    V[12] = GATH(Pd.x); V[13] = GATH(Pd.y); V[14] = GATH(Pd.z);  V[15] = GATH(Pd.w); }
#define ACC16(V, Pa, Pb, Pc, Pd) { \
    ACC(Pa.x, V[0]);  ACC(Pa.y, V[1]);  ACC(Pa.z, V[2]);   ACC(Pa.w, V[3]); \
    ACC(Pb.x, V[4]);  ACC(Pb.y, V[5]);  ACC(Pb.z, V[6]);   ACC(Pb.w, V[7]); \
    ACC(Pc.x, V[8]);  ACC(Pc.y, V[9]);  ACC(Pc.z, V[10]);  ACC(Pc.w, V[11]); \
    ACC(Pd.x, V[12]); ACC(Pd.y, V[13]); ACC(Pd.z, V[14]);  ACC(Pd.w, V[15]); }

    // head: align k to 16 (64 B scalar-load alignment)
    while (k < kend && (k & 15)) {
        const int iw = items[k];
        const __half2 v = GATH(iw);
        ACC(iw, v);
        ++k;
    }

    if (k + 32 <= kend) {
        int4 Aa, Ab, Ac, Ad, Ba, Bb, Bc, Bd;
        __half2 u[16], v[16];
        LOADI(Aa, Ab, Ac, Ad, k);
        GATHER16(u, Aa, Ab, Ac, Ad);
        LOADI(Ba, Bb, Bc, Bd, k + 16);
        k += 32;
        for (;;) {
            // phase 1: issue B's gathers, drain A
            GATHER16(v, Ba, Bb, Bc, Bd);
            ACC16(u, Aa, Ab, Ac, Ad);
            if (k + 16 <= kend) { LOADI(Aa, Ab, Ac, Ad, k); k += 16; }
            else { ACC16(v, Ba, Bb, Bc, Bd); break; }
            // phase 2: issue A's gathers, drain B
            GATHER16(u, Aa, Ab, Ac, Ad);
            ACC16(v, Ba, Bb, Bc, Bd);
            if (k + 16 <= kend) { LOADI(Ba, Bb, Bc, Bd, k); k += 16; }
            else { ACC16(u, Aa, Ab, Ac, Ad); break; }
        }
    }
    // tail
    while (k < kend) {
        const int iw = items[k];
        const __half2 v = GATH(iw);
        ACC(iw, v);
        ++k;
    }

    {   // range ends node-aligned -> cc==0; relu(0)=0 safe
        const float2 f = __half22float2(cc);
        a0 += fmaxf(f.x, 0.f);
        a1 += fmaxf(f.y, 0.f);
    }

    __shared__ float red[4][DDIM];
    red[wv][lane * 2 + 0] = a0;
    red[wv][lane * 2 + 1] = a1;
    __syncthreads();
    const int tid = threadIdx.x;
    if (tid < DDIM) {
        partials[(size_t)blockIdx.x * DDIM + tid] =
            red[0][tid] + red[1][tid] + red[2][tid] + red[3][tid];
    }
}

// ---------------- Kernel C: reduce partials + last-block softmax ----------------
__global__ __launch_bounds__(256) void reduce_softmax(
    const float* __restrict__ partials, float* __restrict__ out2,
    float* __restrict__ out, int* __restrict__ done, int nb)
{
    const int tid = threadIdx.x;
    const int d = tid & (DDIM - 1);
    const int h = tid >> 7;                  // 0..1
    {
        const int rows = nb / RED_BLOCKS;    // 32
        const int r0 = blockIdx.x * rows;
        float s = 0.f;
        for (int r = r0 + h; r < r0 + rows; r += 2)
            s += partials[(size_t)r * DDIM + d];
        __shared__ float red[2][DDIM];
        red[h][d] = s;
        __syncthreads();
        if (tid < DDIM)
            out2[(size_t)blockIdx.x * DDIM + tid] = red[0][tid] + red[1][tid];
    }
    __threadfence();
    __shared__ int isLast;
    if (tid == 0) {
        const int v = atomicAdd(done, 1);
        isLast = (v == RED_BLOCKS - 1) ? 1 : 0;
    }
    __syncthreads();
    if (!isLast) return;
    __threadfence();                          // acquire

    float s = 0.f;
    for (int b = h; b < RED_BLOCKS; b += 2)
        s += out2[(size_t)b * DDIM + d];
    __shared__ float r2[2][DDIM];
    r2[h][d] = s;
    __syncthreads();

    __shared__ float vec[DDIM];
    __shared__ float tmp[DDIM];
    if (tid < DDIM) { const float v = r2[0][tid] + r2[1][tid]; vec[tid] = v; tmp[tid] = v; }
    __syncthreads();
    for (int o = 64; o > 0; o >>= 1) {
        if (tid < o) tmp[tid] = fmaxf(tmp[tid], tmp[tid + o]);
        __syncthreads();
    }
    const float mx = tmp[0];
    __syncthreads();
    float ev = 0.f;
    if (tid < DDIM) { ev = expf(vec[tid] - mx); tmp[tid] = ev; }
    __syncthreads();
    for (int o = 64; o > 0; o >>= 1) {
        if (tid < o) tmp[tid] += tmp[tid + o];
        __syncthreads();
    }
    if (tid < DDIM) out[tid] = ev / tmp[0];
}

extern "C" void kernel_launch(void* const* d_in, const int* in_sizes, int n_in,
                              void* d_out, int out_size, void* d_ws, size_t ws_size,
                              hipStream_t stream) {
    const float* impact        = (const float*)d_in[0];
    const float* W             = (const float*)d_in[1];
    const float* Mm            = (const float*)d_in[2];
    const int*   node_ids      = (const int*)d_in[3];
    const int*   neighbor_ids  = (const int*)d_in[4];
    const int*   neighbor_segs = (const int*)d_in[5];

    const int T = in_sizes[0] / DDIM;   // 10000
    const int N = in_sizes[3];          // 50000
    const int E = in_sizes[4];          // 800000
    const int K = N + E;

    char* ws = (char*)d_ws;
    size_t off = 0;
    const int whoff = (int)off;
    __half* WhH = (__half*)(ws + off);  off += (size_t)T * DDIM * sizeof(__half);   // 2.56 MB
    const int mhoff = (int)off;
    __half* MhH = (__half*)(ws + off);  off += (size_t)T * DDIM * sizeof(__half);   // 2.56 MB
    float* partials = (float*)(ws + off); off += (size_t)ACC_BLOCKS * DDIM * sizeof(float);
    float* part2    = (float*)(ws + off); off += (size_t)RED_BLOCKS * DDIM * sizeof(float);
    int*   done     = (int*)(ws + off);   off += 256;
    off = (off + 255) & ~(size_t)255;                      // align for scalar item loads
    int*   items    = (int*)(ws + off);   off += (size_t)(K + 64) * sizeof(int);
    int*   wstart   = (int*)(ws + off);   off += (size_t)(NWALK + 1) * sizeof(int);
    float* outf     = (float*)d_out;

    const int PB    = (T + 31) / 32;                       // precompute blocks (313)
    const int PREPB = (E + NWALK + 1 + 255) / 256;         // prep blocks (incl. wstart)

    fat_prep_precompute<<<PB + PREPB, 256, 0, stream>>>(
        impact, W, Mm, WhH, MhH, neighbor_segs, node_ids, neighbor_ids,
        items, wstart, done, T, N, E, PB, whoff, mhoff);
    accumulate_items<<<ACC_BLOCKS, 256, 0, stream>>>(ws, items, wstart, partials);
    reduce_softmax<<<RED_BLOCKS, 256, 0, stream>>>(partials, part2, outf, done, ACC_BLOCKS);
}